// Round 1
// baseline (452.821 us; speedup 1.0000x reference)
//
#include <hip/hip_runtime.h>
#include <cstddef>

// EdgeDegreeEmbedding fused kernel for MI355X (gfx950)
//
// Math (derived from the reference):
//   h1 = silu(LN(x_edge @ w1 + b1))          [E,64]
//   h2 = silu(LN(h1 @ w2 + b2))              [E,64]
//   m0 = (h2 @ w3 + b3)                      [E,5,128]
//   out[dst[e], i, c] += env(d_e/12)/5 * sum_a wigner_inv[e, i, wcol[a]] * m0[e,a,c]
//   wcol = {0,2,6,12,20}  (the m=0 column for each l in the full 25-coef listing)
//   out initialized to x.

constexpr int C_DIM   = 128;
constexpr int NCOEF   = 25;
constexpr int M0      = 5;
constexpr int EB      = 8;     // edges per block
constexpr int BT      = 256;   // threads per block
constexpr float EPS_LN      = 1e-5f;
constexpr float INV_CUTOFF  = 1.0f / 12.0f;
constexpr float INV_RESCALE = 0.2f;

__global__ __launch_bounds__(BT) void edge_degree_kernel(
    const float* __restrict__ x_edge,        // [E,128]
    const float* __restrict__ edge_distance, // [E]
    const float* __restrict__ wigner_inv,    // [E,25,25]
    const int*   __restrict__ edge_index,    // [2,E]
    const float* __restrict__ w1, const float* __restrict__ b1,
    const float* __restrict__ g1, const float* __restrict__ be1,
    const float* __restrict__ w2, const float* __restrict__ b2,
    const float* __restrict__ g2, const float* __restrict__ be2,
    const float* __restrict__ w3, const float* __restrict__ b3,
    const int*   __restrict__ node_offset_p,
    float*       __restrict__ out,           // [N,25,128]
    int E)
{
    __shared__ float s_xe[EB][C_DIM];   // 4 KB
    __shared__ float s_h1[EB][64];      // 2 KB
    __shared__ float s_h2[EB][64];      // 2 KB
    __shared__ float s_wig[EB][NCOEF * M0]; // 8*125 floats = 4 KB
    __shared__ float s_scale[EB];
    __shared__ int   s_dst[EB];

    const int t   = threadIdx.x;
    const int blk = blockIdx.x;
    const int g0  = blk * EB;
    const int ne  = (E - g0) < EB ? (E - g0) : EB;   // valid edges this block

    // ---- stage x_edge tile (contiguous: rows g0..g0+7) ----
    {
        const float* src = x_edge + (size_t)g0 * C_DIM;
        const int total = EB * C_DIM;
        for (int f = t; f < total; f += BT) {
            int e = f >> 7;
            ((float*)s_xe)[f] = (e < ne) ? src[f] : 0.0f;
        }
    }

    // ---- gather wigner columns wcol = {0,2,6,12,20} for i in [0,25) ----
    {
        const int wcol_[M0] = {0, 2, 6, 12, 20};
        const int total = EB * NCOEF * M0; // 1000
        for (int f = t; f < total; f += BT) {
            int e = f / 125;
            int r = f - e * 125;
            int i = r / 5;
            int a = r - i * 5;
            float v = 0.0f;
            if (e < ne)
                v = wigner_inv[((size_t)(g0 + e)) * (NCOEF * NCOEF) + i * NCOEF + wcol_[a]];
            s_wig[e][r] = v;
        }
    }

    // ---- per-edge envelope scale + dst ----
    if (t < EB) {
        if (t < ne) {
            float d  = edge_distance[g0 + t] * INV_CUTOFF;
            float d2 = d * d;
            float d5 = d2 * d2 * d;
            float env = 1.0f + d5 * (-21.0f + d * (35.0f + d * (-15.0f)));
            env = (d < 1.0f) ? env : 0.0f;
            s_scale[t] = env * INV_RESCALE;
            s_dst[t]   = edge_index[E + g0 + t] - node_offset_p[0];
        } else {
            s_scale[t] = 0.0f;
            s_dst[t]   = 0;
        }
    }
    __syncthreads();

    const int lane = t & 63;
    const int wv   = t >> 6;    // wave 0..3; wave wv handles edges {wv, wv+4}
    const int j    = lane;      // hidden-unit index

    // ---- phase 1: h1 = silu(LN(xe @ w1 + b1)) ----
    {
        float acc0 = b1[j], acc1 = acc0;
        const float g = g1[j], be = be1[j];
        for (int k = 0; k < C_DIM; ++k) {
            float w = w1[k * 64 + j];
            acc0 += s_xe[wv][k] * w;
            acc1 += s_xe[wv + 4][k] * w;
        }
        float accs[2] = {acc0, acc1};
        #pragma unroll
        for (int ei = 0; ei < 2; ++ei) {
            int e = wv + 4 * ei;
            float v = accs[ei];
            float s = v;
            #pragma unroll
            for (int o = 32; o; o >>= 1) s += __shfl_xor(s, o, 64);
            float mu = s * (1.0f / 64.0f);
            float dv = v - mu;
            float q  = dv * dv;
            #pragma unroll
            for (int o = 32; o; o >>= 1) q += __shfl_xor(q, o, 64);
            float rstd = rsqrtf(q * (1.0f / 64.0f) + EPS_LN);
            float z = dv * rstd * g + be;
            float r = z / (1.0f + __expf(-z));
            s_h1[e][j] = r;
        }
    }
    __syncthreads();

    // ---- phase 2: h2 = silu(LN(h1 @ w2 + b2)) ----
    {
        float acc0 = b2[j], acc1 = acc0;
        const float g = g2[j], be = be2[j];
        for (int k = 0; k < 64; ++k) {
            float w = w2[k * 64 + j];
            acc0 += s_h1[wv][k] * w;
            acc1 += s_h1[wv + 4][k] * w;
        }
        float accs[2] = {acc0, acc1};
        #pragma unroll
        for (int ei = 0; ei < 2; ++ei) {
            int e = wv + 4 * ei;
            float v = accs[ei];
            float s = v;
            #pragma unroll
            for (int o = 32; o; o >>= 1) s += __shfl_xor(s, o, 64);
            float mu = s * (1.0f / 64.0f);
            float dv = v - mu;
            float q  = dv * dv;
            #pragma unroll
            for (int o = 32; o; o >>= 1) q += __shfl_xor(q, o, 64);
            float rstd = rsqrtf(q * (1.0f / 64.0f) + EPS_LN);
            float z = dv * rstd * g + be;
            float r = z / (1.0f + __expf(-z));
            s_h2[e][j] = r;
        }
    }
    __syncthreads();

    // ---- phase 3: m0 (kept in registers) ----
    // thread -> c = t&127, half = t>>7; handles edges e = half + 2*ei, ei in [0,4)
    const int c    = t & 127;
    const int half = t >> 7;
    float m0r[4][M0];
    #pragma unroll
    for (int a = 0; a < M0; ++a) {
        float bb = b3[a * C_DIM + c];
        float a0 = bb, a1 = bb, a2 = bb, a3 = bb;
        const float* w3c = w3 + a * C_DIM + c;
        for (int k = 0; k < 64; ++k) {
            float w = w3c[k * (M0 * C_DIM)];
            a0 += s_h2[half + 0][k] * w;
            a1 += s_h2[half + 2][k] * w;
            a2 += s_h2[half + 4][k] * w;
            a3 += s_h2[half + 6][k] * w;
        }
        m0r[0][a] = a0; m0r[1][a] = a1; m0r[2][a] = a2; m0r[3][a] = a3;
    }

    // ---- phase 4: wigner contraction + envelope + atomic scatter ----
    #pragma unroll
    for (int ei = 0; ei < 4; ++ei) {
        const int e = half + 2 * ei;
        if (e >= ne) continue;
        const float sc = s_scale[e];
        float* obase = out + (size_t)s_dst[e] * (NCOEF * C_DIM) + c;
        #pragma unroll
        for (int i = 0; i < NCOEF; ++i) {
            const float* wg = &s_wig[e][i * M0];
            float v = wg[0] * m0r[ei][0] + wg[1] * m0r[ei][1] + wg[2] * m0r[ei][2]
                    + wg[3] * m0r[ei][3] + wg[4] * m0r[ei][4];
            atomicAdd(obase + i * C_DIM, v * sc);
        }
    }
}

extern "C" void kernel_launch(void* const* d_in, const int* in_sizes, int n_in,
                              void* d_out, int out_size, void* d_ws, size_t ws_size,
                              hipStream_t stream)
{
    const float* x             = (const float*)d_in[0];
    const float* x_edge        = (const float*)d_in[1];
    const float* edge_distance = (const float*)d_in[2];
    const float* wigner_inv    = (const float*)d_in[3];
    const int*   edge_index    = (const int*)d_in[4];
    const float* w1  = (const float*)d_in[5];
    const float* b1  = (const float*)d_in[6];
    const float* g1  = (const float*)d_in[7];
    const float* be1 = (const float*)d_in[8];
    const float* w2  = (const float*)d_in[9];
    const float* b2  = (const float*)d_in[10];
    const float* g2  = (const float*)d_in[11];
    const float* be2 = (const float*)d_in[12];
    const float* w3  = (const float*)d_in[13];
    const float* b3  = (const float*)d_in[14];
    const int*   node_offset = (const int*)d_in[15];

    float* out = (float*)d_out;
    const int E = in_sizes[1] / C_DIM;

    // out = x  (copy; the scatter kernel accumulates on top)
    hipMemcpyAsync(out, x, (size_t)out_size * sizeof(float),
                   hipMemcpyDeviceToDevice, stream);

    const int grid = (E + EB - 1) / EB;
    edge_degree_kernel<<<grid, BT, 0, stream>>>(
        x_edge, edge_distance, wigner_inv, edge_index,
        w1, b1, g1, be1, w2, b2, g2, be2, w3, b3,
        node_offset, out, E);
}

// Round 2
// 412.198 us; speedup vs baseline: 1.0986x; 1.0986x over previous
//
#include <hip/hip_runtime.h>
#include <cstddef>

// EdgeDegreeEmbedding fused pipeline for MI355X (gfx950)
//
// Math (derived from the reference):
//   h1 = silu(LN(x_edge @ w1 + b1))          [E,64]
//   h2 = silu(LN(h1 @ w2 + b2))              [E,64]
//   m0 = (h2 @ w3 + b3) * env(d/12)/5        [E,5,128]   (scaled in kernel A)
//   out[dst[e], i, c] += sum_a wigner_inv[e, i, wcol[a]] * m0[e,a,c]
//   wcol = {0,2,6,12,20}; out initialized to x.
//
// Round-2 structure: no atomics. Kernel A writes m0 to ws; edges are binned
// by dst (count/scan/fill); kernel B accumulates per-node in registers and
// writes out = x + acc exactly once.

constexpr int C_DIM   = 128;
constexpr int NCOEF   = 25;
constexpr int M0d     = 5;
constexpr float EPS_LN      = 1e-5f;
constexpr float INV_CUTOFF  = 1.0f / 12.0f;
constexpr float INV_RESCALE = 0.2f;

constexpr int EB = 16;    // edges per block (kernel A)
constexpr int BT = 256;

__device__ __forceinline__ float ln_silu(float v, float g, float be) {
    float s = v;
    #pragma unroll
    for (int o = 32; o; o >>= 1) s += __shfl_xor(s, o, 64);
    float mu = s * (1.0f / 64.0f);
    float dv = v - mu;
    float q  = dv * dv;
    #pragma unroll
    for (int o = 32; o; o >>= 1) q += __shfl_xor(q, o, 64);
    float rstd = rsqrtf(q * (1.0f / 64.0f) + EPS_LN);
    float z = dv * rstd * g + be;
    return z / (1.0f + __expf(-z));
}

// ---------------- Kernel A: radial MLP -> scaled m0 ----------------
__global__ __launch_bounds__(BT) void mlp_kernel(
    const float* __restrict__ x_edge,        // [E,128]
    const float* __restrict__ edge_distance, // [E]
    const float* __restrict__ w1, const float* __restrict__ b1,
    const float* __restrict__ g1, const float* __restrict__ be1,
    const float* __restrict__ w2, const float* __restrict__ b2,
    const float* __restrict__ g2, const float* __restrict__ be2,
    const float* __restrict__ w3, const float* __restrict__ b3,
    float*       __restrict__ m0s,           // [E,5,128]
    int E)
{
    __shared__ float s_xe[EB][C_DIM];  // 8 KB
    __shared__ float s_h1[EB][64];     // 4 KB
    __shared__ float s_h2[EB][64];     // 4 KB
    __shared__ float s_scale[EB];

    const int t  = threadIdx.x;
    const int g0 = blockIdx.x * EB;
    const int ne = (E - g0) < EB ? (E - g0) : EB;

    // stage x_edge rows (contiguous)
    {
        const float* src = x_edge + (size_t)g0 * C_DIM;
        for (int f = t; f < EB * C_DIM; f += BT) {
            int e = f >> 7;
            ((float*)s_xe)[f] = (e < ne) ? src[f] : 0.0f;
        }
    }
    if (t < EB) {
        float sc = 0.0f;
        if (t < ne) {
            float d  = edge_distance[g0 + t] * INV_CUTOFF;
            float d2 = d * d;
            float d5 = d2 * d2 * d;
            float env = 1.0f + d5 * (-21.0f + d * (35.0f + d * (-15.0f)));
            sc = ((d < 1.0f) ? env : 0.0f) * INV_RESCALE;
        }
        s_scale[t] = sc;
    }
    __syncthreads();

    const int wv = t >> 6;   // wave: handles edges {wv, wv+4, wv+8, wv+12}
    const int j  = t & 63;   // hidden unit

    // ---- phase 1: h1 = silu(LN(xe @ w1 + b1)) ----
    {
        const float bb = b1[j];
        float acc[4] = {bb, bb, bb, bb};
        #pragma unroll 8
        for (int k = 0; k < C_DIM; k += 4) {
            float4 w;
            w.x = w1[(k + 0) * 64 + j];
            w.y = w1[(k + 1) * 64 + j];
            w.z = w1[(k + 2) * 64 + j];
            w.w = w1[(k + 3) * 64 + j];
            #pragma unroll
            for (int ei = 0; ei < 4; ++ei) {
                float4 xv = *(const float4*)&s_xe[wv + 4 * ei][k];
                acc[ei] += xv.x * w.x + xv.y * w.y + xv.z * w.z + xv.w * w.w;
            }
        }
        const float g = g1[j], be = be1[j];
        #pragma unroll
        for (int ei = 0; ei < 4; ++ei)
            s_h1[wv + 4 * ei][j] = ln_silu(acc[ei], g, be);
    }
    __syncthreads();

    // ---- phase 2: h2 = silu(LN(h1 @ w2 + b2)) ----
    {
        const float bb = b2[j];
        float acc[4] = {bb, bb, bb, bb};
        #pragma unroll 8
        for (int k = 0; k < 64; k += 4) {
            float4 w;
            w.x = w2[(k + 0) * 64 + j];
            w.y = w2[(k + 1) * 64 + j];
            w.z = w2[(k + 2) * 64 + j];
            w.w = w2[(k + 3) * 64 + j];
            #pragma unroll
            for (int ei = 0; ei < 4; ++ei) {
                float4 hv = *(const float4*)&s_h1[wv + 4 * ei][k];
                acc[ei] += hv.x * w.x + hv.y * w.y + hv.z * w.z + hv.w * w.w;
            }
        }
        const float g = g2[j], be = be2[j];
        #pragma unroll
        for (int ei = 0; ei < 4; ++ei)
            s_h2[wv + 4 * ei][j] = ln_silu(acc[ei], g, be);
    }
    __syncthreads();

    // ---- phase 3: m0 = h2 @ w3 + b3, scaled, to global ----
    // thread -> c = t&127, half = t>>7; edges e = half + 2*ei, ei in [0,8)
    {
        const int c    = t & 127;
        const int half = t >> 7;
        float acc[8][5];
        #pragma unroll
        for (int a = 0; a < M0d; ++a) {
            float bb = b3[a * C_DIM + c];
            #pragma unroll
            for (int ei = 0; ei < 8; ++ei) acc[ei][a] = bb;
        }
        #pragma unroll 4
        for (int k = 0; k < 64; k += 4) {
            float4 hv[8];
            #pragma unroll
            for (int ei = 0; ei < 8; ++ei)
                hv[ei] = *(const float4*)&s_h2[half + 2 * ei][k];
            #pragma unroll
            for (int a = 0; a < M0d; ++a) {
                float4 w;
                w.x = w3[(k + 0) * (M0d * C_DIM) + a * C_DIM + c];
                w.y = w3[(k + 1) * (M0d * C_DIM) + a * C_DIM + c];
                w.z = w3[(k + 2) * (M0d * C_DIM) + a * C_DIM + c];
                w.w = w3[(k + 3) * (M0d * C_DIM) + a * C_DIM + c];
                #pragma unroll
                for (int ei = 0; ei < 8; ++ei)
                    acc[ei][a] += hv[ei].x * w.x + hv[ei].y * w.y
                                + hv[ei].z * w.z + hv[ei].w * w.w;
            }
        }
        #pragma unroll
        for (int ei = 0; ei < 8; ++ei) {
            int e = half + 2 * ei;
            if (e < ne) {
                float sc = s_scale[e];
                float* dst = m0s + (size_t)(g0 + e) * (M0d * C_DIM) + c;
                #pragma unroll
                for (int a = 0; a < M0d; ++a) dst[a * C_DIM] = acc[ei][a] * sc;
            }
        }
    }
}

// ---------------- Binning ----------------
__global__ __launch_bounds__(256) void count_kernel(
    const int* __restrict__ edge_index, const int* __restrict__ noff,
    int* __restrict__ cnt, int E, int N)
{
    int e = blockIdx.x * 256 + threadIdx.x;
    if (e < E) {
        int d = edge_index[E + e] - noff[0];
        if (d >= 0 && d < N) atomicAdd(&cnt[d], 1);
    }
}

__global__ __launch_bounds__(256) void scan_kernel(
    const int* __restrict__ cnt, int* __restrict__ offs, int N)
{
    __shared__ int buf[256];
    __shared__ int s_run;
    const int t = threadIdx.x;
    if (t == 0) { offs[0] = 0; s_run = 0; }
    __syncthreads();
    for (int base = 0; base < N; base += 256) {
        int v = (base + t < N) ? cnt[base + t] : 0;
        buf[t] = v;
        __syncthreads();
        for (int off = 1; off < 256; off <<= 1) {
            int u = (t >= off) ? buf[t - off] : 0;
            __syncthreads();
            buf[t] += u;
            __syncthreads();
        }
        if (base + t < N) offs[base + t + 1] = s_run + buf[t];
        __syncthreads();
        if (t == 255) s_run += buf[255];
        __syncthreads();
    }
}

__global__ __launch_bounds__(256) void fill_kernel(
    const int* __restrict__ edge_index, const int* __restrict__ noff,
    const int* __restrict__ offs, int* __restrict__ cur,
    int* __restrict__ perm, int E, int N)
{
    int e = blockIdx.x * 256 + threadIdx.x;
    if (e < E) {
        int d = edge_index[E + e] - noff[0];
        if (d >= 0 && d < N) {
            int p = atomicAdd(&cur[d], 1);
            perm[offs[d] + p] = e;
        }
    }
}

// ---------------- Kernel B: per-node gather-accumulate ----------------
__global__ __launch_bounds__(128) void gather_kernel(
    const float* __restrict__ x,          // [N,25,128]
    const float* __restrict__ m0s,        // [E,5,128] (already scaled)
    const float* __restrict__ wigner_inv, // [E,25,25]
    const int*   __restrict__ perm, const int* __restrict__ offs,
    float*       __restrict__ out, int N)
{
    const int n = blockIdx.x;
    const int t = threadIdx.x;    // channel c
    float acc[NCOEF];
    #pragma unroll
    for (int i = 0; i < NCOEF; ++i) acc[i] = 0.0f;

    const int beg = offs[n], end = offs[n + 1];
    for (int ii = beg; ii < end; ++ii) {
        int e = __builtin_amdgcn_readfirstlane(perm[ii]);
        const float* wrow = wigner_inv + (size_t)e * (NCOEF * NCOEF);
        const float* mb   = m0s + (size_t)e * (M0d * C_DIM) + t;
        float m[M0d];
        #pragma unroll
        for (int a = 0; a < M0d; ++a) m[a] = mb[a * C_DIM];
        // wrow indices are wave-uniform -> scalar loads, no LDS/barriers
        #pragma unroll
        for (int i = 0; i < NCOEF; ++i) {
            acc[i] += wrow[i * NCOEF + 0]  * m[0]
                    + wrow[i * NCOEF + 2]  * m[1]
                    + wrow[i * NCOEF + 6]  * m[2]
                    + wrow[i * NCOEF + 12] * m[3]
                    + wrow[i * NCOEF + 20] * m[4];
        }
    }
    const size_t base = (size_t)n * (NCOEF * C_DIM) + t;
    #pragma unroll
    for (int i = 0; i < NCOEF; ++i)
        out[base + i * C_DIM] = x[base + i * C_DIM] + acc[i];
}

// ---------------- Fallback (round-1 atomic version) ----------------
constexpr int FEB = 8;

__global__ __launch_bounds__(BT) void edge_degree_fallback(
    const float* __restrict__ x_edge, const float* __restrict__ edge_distance,
    const float* __restrict__ wigner_inv, const int* __restrict__ edge_index,
    const float* __restrict__ w1, const float* __restrict__ b1,
    const float* __restrict__ g1, const float* __restrict__ be1,
    const float* __restrict__ w2, const float* __restrict__ b2,
    const float* __restrict__ g2, const float* __restrict__ be2,
    const float* __restrict__ w3, const float* __restrict__ b3,
    const int* __restrict__ node_offset_p, float* __restrict__ out, int E)
{
    __shared__ float s_xe[FEB][C_DIM];
    __shared__ float s_h1[FEB][64];
    __shared__ float s_h2[FEB][64];
    __shared__ float s_wig[FEB][NCOEF * M0d];
    __shared__ float s_scale[FEB];
    __shared__ int   s_dst[FEB];

    const int t = threadIdx.x;
    const int g0 = blockIdx.x * FEB;
    const int ne = (E - g0) < FEB ? (E - g0) : FEB;

    {
        const float* src = x_edge + (size_t)g0 * C_DIM;
        for (int f = t; f < FEB * C_DIM; f += BT) {
            int e = f >> 7;
            ((float*)s_xe)[f] = (e < ne) ? src[f] : 0.0f;
        }
    }
    {
        const int wcol_[M0d] = {0, 2, 6, 12, 20};
        for (int f = t; f < FEB * NCOEF * M0d; f += BT) {
            int e = f / 125, r = f - e * 125, i = r / 5, a = r - i * 5;
            float v = 0.0f;
            if (e < ne)
                v = wigner_inv[((size_t)(g0 + e)) * (NCOEF * NCOEF) + i * NCOEF + wcol_[a]];
            s_wig[e][r] = v;
        }
    }
    if (t < FEB) {
        if (t < ne) {
            float d = edge_distance[g0 + t] * INV_CUTOFF;
            float d2 = d * d, d5 = d2 * d2 * d;
            float env = 1.0f + d5 * (-21.0f + d * (35.0f + d * (-15.0f)));
            s_scale[t] = ((d < 1.0f) ? env : 0.0f) * INV_RESCALE;
            s_dst[t] = edge_index[E + g0 + t] - node_offset_p[0];
        } else { s_scale[t] = 0.0f; s_dst[t] = 0; }
    }
    __syncthreads();

    const int wv = t >> 6, j = t & 63;
    {
        float acc0 = b1[j], acc1 = acc0;
        for (int k = 0; k < C_DIM; ++k) {
            float w = w1[k * 64 + j];
            acc0 += s_xe[wv][k] * w;
            acc1 += s_xe[wv + 4][k] * w;
        }
        const float g = g1[j], be = be1[j];
        s_h1[wv][j]     = ln_silu(acc0, g, be);
        s_h1[wv + 4][j] = ln_silu(acc1, g, be);
    }
    __syncthreads();
    {
        float acc0 = b2[j], acc1 = acc0;
        for (int k = 0; k < 64; ++k) {
            float w = w2[k * 64 + j];
            acc0 += s_h1[wv][k] * w;
            acc1 += s_h1[wv + 4][k] * w;
        }
        const float g = g2[j], be = be2[j];
        s_h2[wv][j]     = ln_silu(acc0, g, be);
        s_h2[wv + 4][j] = ln_silu(acc1, g, be);
    }
    __syncthreads();

    const int c = t & 127, half = t >> 7;
    float m0r[4][M0d];
    #pragma unroll
    for (int a = 0; a < M0d; ++a) {
        float bb = b3[a * C_DIM + c];
        float a0 = bb, a1 = bb, a2 = bb, a3 = bb;
        const float* w3c = w3 + a * C_DIM + c;
        for (int k = 0; k < 64; ++k) {
            float w = w3c[k * (M0d * C_DIM)];
            a0 += s_h2[half + 0][k] * w;
            a1 += s_h2[half + 2][k] * w;
            a2 += s_h2[half + 4][k] * w;
            a3 += s_h2[half + 6][k] * w;
        }
        m0r[0][a] = a0; m0r[1][a] = a1; m0r[2][a] = a2; m0r[3][a] = a3;
    }
    #pragma unroll
    for (int ei = 0; ei < 4; ++ei) {
        const int e = half + 2 * ei;
        if (e >= ne) continue;
        const float sc = s_scale[e];
        float* obase = out + (size_t)s_dst[e] * (NCOEF * C_DIM) + c;
        #pragma unroll
        for (int i = 0; i < NCOEF; ++i) {
            const float* wg = &s_wig[e][i * M0d];
            float v = wg[0] * m0r[ei][0] + wg[1] * m0r[ei][1] + wg[2] * m0r[ei][2]
                    + wg[3] * m0r[ei][3] + wg[4] * m0r[ei][4];
            atomicAdd(obase + i * C_DIM, v * sc);
        }
    }
}

extern "C" void kernel_launch(void* const* d_in, const int* in_sizes, int n_in,
                              void* d_out, int out_size, void* d_ws, size_t ws_size,
                              hipStream_t stream)
{
    const float* x             = (const float*)d_in[0];
    const float* x_edge        = (const float*)d_in[1];
    const float* edge_distance = (const float*)d_in[2];
    const float* wigner_inv    = (const float*)d_in[3];
    const int*   edge_index    = (const int*)d_in[4];
    const float* w1  = (const float*)d_in[5];
    const float* b1  = (const float*)d_in[6];
    const float* g1  = (const float*)d_in[7];
    const float* be1 = (const float*)d_in[8];
    const float* w2  = (const float*)d_in[9];
    const float* b2  = (const float*)d_in[10];
    const float* g2  = (const float*)d_in[11];
    const float* be2 = (const float*)d_in[12];
    const float* w3  = (const float*)d_in[13];
    const float* b3  = (const float*)d_in[14];
    const int*   node_offset = (const int*)d_in[15];

    float* out = (float*)d_out;
    const int E = in_sizes[1] / C_DIM;
    const int N = in_sizes[0] / (NCOEF * C_DIM);

    const size_t m0_bytes  = (size_t)E * (M0d * C_DIM) * 4;
    const size_t cnt_off   = m0_bytes;
    const size_t cur_off   = cnt_off + (size_t)N * 4;
    const size_t offs_off  = cur_off + (size_t)N * 4;
    const size_t perm_off  = offs_off + (size_t)(N + 1) * 4;
    const size_t need      = perm_off + (size_t)E * 4;

    if (ws_size >= need) {
        char* ws  = (char*)d_ws;
        float* m0s = (float*)ws;
        int* cnt  = (int*)(ws + cnt_off);
        int* cur  = (int*)(ws + cur_off);
        int* offs = (int*)(ws + offs_off);
        int* perm = (int*)(ws + perm_off);

        hipMemsetAsync(cnt, 0, (size_t)N * 8, stream);  // cnt + cur (adjacent)

        count_kernel<<<(E + 255) / 256, 256, 0, stream>>>(edge_index, node_offset, cnt, E, N);
        scan_kernel<<<1, 256, 0, stream>>>(cnt, offs, N);
        fill_kernel<<<(E + 255) / 256, 256, 0, stream>>>(edge_index, node_offset, offs, cur, perm, E, N);

        mlp_kernel<<<(E + EB - 1) / EB, BT, 0, stream>>>(
            x_edge, edge_distance,
            w1, b1, g1, be1, w2, b2, g2, be2, w3, b3, m0s, E);

        gather_kernel<<<N, 128, 0, stream>>>(x, m0s, wigner_inv, perm, offs, out, N);
    } else {
        hipMemcpyAsync(out, x, (size_t)out_size * sizeof(float),
                       hipMemcpyDeviceToDevice, stream);
        edge_degree_fallback<<<(E + FEB - 1) / FEB, BT, 0, stream>>>(
            x_edge, edge_distance, wigner_inv, edge_index,
            w1, b1, g1, be1, w2, b2, g2, be2, w3, b3,
            node_offset, out, E);
    }
}

// Round 3
// 224.955 us; speedup vs baseline: 2.0129x; 1.8324x over previous
//
#include <hip/hip_runtime.h>
#include <cstddef>

// EdgeDegreeEmbedding fused pipeline for MI355X (gfx950)
//
// Math (derived from the reference):
//   h1 = silu(LN(x_edge @ w1 + b1))          [E,64]
//   h2 = silu(LN(h1 @ w2 + b2))              [E,64]
//   m0 = (h2 @ w3 + b3) * env(d/12)/5        [E,5,128]   (scaled in kernel A)
//   out[dst[e], i, c] += sum_a wigner_inv[e, i, a*(a+1)] * m0[e,a,c]
//   out initialized to x.
//
// Round-3: kernel B software-pipelined; wigner gathered with per-lane vector
// loads into double-buffered LDS (no scalar-load latency chains, no atomics).

constexpr int C_DIM   = 128;
constexpr int NCOEF   = 25;
constexpr int M0d     = 5;
constexpr float EPS_LN      = 1e-5f;
constexpr float INV_CUTOFF  = 1.0f / 12.0f;
constexpr float INV_RESCALE = 0.2f;

constexpr int EB = 16;    // edges per block (kernel A)
constexpr int BT = 256;

__device__ __forceinline__ float ln_silu(float v, float g, float be) {
    float s = v;
    #pragma unroll
    for (int o = 32; o; o >>= 1) s += __shfl_xor(s, o, 64);
    float mu = s * (1.0f / 64.0f);
    float dv = v - mu;
    float q  = dv * dv;
    #pragma unroll
    for (int o = 32; o; o >>= 1) q += __shfl_xor(q, o, 64);
    float rstd = rsqrtf(q * (1.0f / 64.0f) + EPS_LN);
    float z = dv * rstd * g + be;
    return z / (1.0f + __expf(-z));
}

// ---------------- Kernel A: radial MLP -> scaled m0 ----------------
__global__ __launch_bounds__(BT) void mlp_kernel(
    const float* __restrict__ x_edge,        // [E,128]
    const float* __restrict__ edge_distance, // [E]
    const float* __restrict__ w1, const float* __restrict__ b1,
    const float* __restrict__ g1, const float* __restrict__ be1,
    const float* __restrict__ w2, const float* __restrict__ b2,
    const float* __restrict__ g2, const float* __restrict__ be2,
    const float* __restrict__ w3, const float* __restrict__ b3,
    float*       __restrict__ m0s,           // [E,5,128]
    int E)
{
    __shared__ float s_xe[EB][C_DIM];  // 8 KB
    __shared__ float s_h1[EB][64];     // 4 KB
    __shared__ float s_h2[EB][64];     // 4 KB
    __shared__ float s_scale[EB];

    const int t  = threadIdx.x;
    const int g0 = blockIdx.x * EB;
    const int ne = (E - g0) < EB ? (E - g0) : EB;

    {
        const float* src = x_edge + (size_t)g0 * C_DIM;
        for (int f = t; f < EB * C_DIM; f += BT) {
            int e = f >> 7;
            ((float*)s_xe)[f] = (e < ne) ? src[f] : 0.0f;
        }
    }
    if (t < EB) {
        float sc = 0.0f;
        if (t < ne) {
            float d  = edge_distance[g0 + t] * INV_CUTOFF;
            float d2 = d * d;
            float d5 = d2 * d2 * d;
            float env = 1.0f + d5 * (-21.0f + d * (35.0f + d * (-15.0f)));
            sc = ((d < 1.0f) ? env : 0.0f) * INV_RESCALE;
        }
        s_scale[t] = sc;
    }
    __syncthreads();

    const int wv = t >> 6;   // wave: handles edges {wv, wv+4, wv+8, wv+12}
    const int j  = t & 63;   // hidden unit

    // ---- phase 1: h1 = silu(LN(xe @ w1 + b1)) ----
    {
        const float bb = b1[j];
        float acc[4] = {bb, bb, bb, bb};
        #pragma unroll 8
        for (int k = 0; k < C_DIM; k += 4) {
            float4 w;
            w.x = w1[(k + 0) * 64 + j];
            w.y = w1[(k + 1) * 64 + j];
            w.z = w1[(k + 2) * 64 + j];
            w.w = w1[(k + 3) * 64 + j];
            #pragma unroll
            for (int ei = 0; ei < 4; ++ei) {
                float4 xv = *(const float4*)&s_xe[wv + 4 * ei][k];
                acc[ei] += xv.x * w.x + xv.y * w.y + xv.z * w.z + xv.w * w.w;
            }
        }
        const float g = g1[j], be = be1[j];
        #pragma unroll
        for (int ei = 0; ei < 4; ++ei)
            s_h1[wv + 4 * ei][j] = ln_silu(acc[ei], g, be);
    }
    __syncthreads();

    // ---- phase 2: h2 = silu(LN(h1 @ w2 + b2)) ----
    {
        const float bb = b2[j];
        float acc[4] = {bb, bb, bb, bb};
        #pragma unroll 8
        for (int k = 0; k < 64; k += 4) {
            float4 w;
            w.x = w2[(k + 0) * 64 + j];
            w.y = w2[(k + 1) * 64 + j];
            w.z = w2[(k + 2) * 64 + j];
            w.w = w2[(k + 3) * 64 + j];
            #pragma unroll
            for (int ei = 0; ei < 4; ++ei) {
                float4 hv = *(const float4*)&s_h1[wv + 4 * ei][k];
                acc[ei] += hv.x * w.x + hv.y * w.y + hv.z * w.z + hv.w * w.w;
            }
        }
        const float g = g2[j], be = be2[j];
        #pragma unroll
        for (int ei = 0; ei < 4; ++ei)
            s_h2[wv + 4 * ei][j] = ln_silu(acc[ei], g, be);
    }
    __syncthreads();

    // ---- phase 3: m0 = h2 @ w3 + b3, scaled, to global ----
    {
        const int c    = t & 127;
        const int half = t >> 7;
        float acc[8][5];
        #pragma unroll
        for (int a = 0; a < M0d; ++a) {
            float bb = b3[a * C_DIM + c];
            #pragma unroll
            for (int ei = 0; ei < 8; ++ei) acc[ei][a] = bb;
        }
        #pragma unroll 4
        for (int k = 0; k < 64; k += 4) {
            float4 hv[8];
            #pragma unroll
            for (int ei = 0; ei < 8; ++ei)
                hv[ei] = *(const float4*)&s_h2[half + 2 * ei][k];
            #pragma unroll
            for (int a = 0; a < M0d; ++a) {
                float4 w;
                w.x = w3[(k + 0) * (M0d * C_DIM) + a * C_DIM + c];
                w.y = w3[(k + 1) * (M0d * C_DIM) + a * C_DIM + c];
                w.z = w3[(k + 2) * (M0d * C_DIM) + a * C_DIM + c];
                w.w = w3[(k + 3) * (M0d * C_DIM) + a * C_DIM + c];
                #pragma unroll
                for (int ei = 0; ei < 8; ++ei)
                    acc[ei][a] += hv[ei].x * w.x + hv[ei].y * w.y
                                + hv[ei].z * w.z + hv[ei].w * w.w;
            }
        }
        #pragma unroll
        for (int ei = 0; ei < 8; ++ei) {
            int e = half + 2 * ei;
            if (e < ne) {
                float sc = s_scale[e];
                float* dst = m0s + (size_t)(g0 + e) * (M0d * C_DIM) + c;
                #pragma unroll
                for (int a = 0; a < M0d; ++a) dst[a * C_DIM] = acc[ei][a] * sc;
            }
        }
    }
}

// ---------------- Binning ----------------
__global__ __launch_bounds__(256) void count_kernel(
    const int* __restrict__ edge_index, const int* __restrict__ noff,
    int* __restrict__ cnt, int E, int N)
{
    int e = blockIdx.x * 256 + threadIdx.x;
    if (e < E) {
        int d = edge_index[E + e] - noff[0];
        if (d >= 0 && d < N) atomicAdd(&cnt[d], 1);
    }
}

__global__ __launch_bounds__(256) void scan_kernel(
    const int* __restrict__ cnt, int* __restrict__ offs, int N)
{
    __shared__ int buf[256];
    __shared__ int s_run;
    const int t = threadIdx.x;
    if (t == 0) { offs[0] = 0; s_run = 0; }
    __syncthreads();
    for (int base = 0; base < N; base += 256) {
        int v = (base + t < N) ? cnt[base + t] : 0;
        buf[t] = v;
        __syncthreads();
        for (int off = 1; off < 256; off <<= 1) {
            int u = (t >= off) ? buf[t - off] : 0;
            __syncthreads();
            buf[t] += u;
            __syncthreads();
        }
        if (base + t < N) offs[base + t + 1] = s_run + buf[t];
        __syncthreads();
        if (t == 255) s_run += buf[255];
        __syncthreads();
    }
}

__global__ __launch_bounds__(256) void fill_kernel(
    const int* __restrict__ edge_index, const int* __restrict__ noff,
    const int* __restrict__ offs, int* __restrict__ cur,
    int* __restrict__ perm, int E, int N)
{
    int e = blockIdx.x * 256 + threadIdx.x;
    if (e < E) {
        int d = edge_index[E + e] - noff[0];
        if (d >= 0 && d < N) {
            int p = atomicAdd(&cur[d], 1);
            perm[offs[d] + p] = e;
        }
    }
}

// ---------------- Kernel B: per-node gather, software-pipelined ----------------
// 128 threads (2 waves) per node. Per edge: 125 wigner values loaded with ONE
// per-lane vector load (lane l -> row l/5, col (l%5)(l%5+1)), staged to a
// double-buffered LDS tile [5][28] (transposed, padded for float4 reads).
// Next edge's W and m0 loads are issued before computing the current edge.
__global__ __launch_bounds__(128) void gather_kernel(
    const float* __restrict__ x,          // [N,25,128]
    const float* __restrict__ m0s,        // [E,5,128] (already scaled)
    const float* __restrict__ wigner_inv, // [E,25,25]
    const int*   __restrict__ perm, const int* __restrict__ offs,
    float*       __restrict__ out, int N)
{
    __shared__ float s_w[2][M0d][28];   // 1.1 KB

    const int n = blockIdx.x;
    const int t = threadIdx.x;          // channel c; also W-load lane
    const int wa = t % 5;               // a index for W load (t<125)
    const int wi = t / 5;               // i index for W load
    const int wco = wa * (wa + 1);      // wcol = {0,2,6,12,20}

    // zero the padding columns i=25..27 (written once, never overwritten)
    if (t < 2 * M0d * 3) {
        int b = t / 15, r = t % 15;
        s_w[b][r / 3][25 + r % 3] = 0.0f;
    }

    float acc[28];
    #pragma unroll
    for (int i = 0; i < 28; ++i) acc[i] = 0.0f;

    const int beg = offs[n], end = offs[n + 1];
    const int cnt = end - beg;

    float wc = 0.0f;
    float mc[M0d];
    #pragma unroll
    for (int a = 0; a < M0d; ++a) mc[a] = 0.0f;

    if (cnt > 0) {
        int e = perm[beg];
        if (t < 125) wc = wigner_inv[(size_t)e * 625 + wi * 25 + wco];
        const float* mb = m0s + (size_t)e * (M0d * C_DIM) + t;
        #pragma unroll
        for (int a = 0; a < M0d; ++a) mc[a] = mb[a * C_DIM];
    }

    int buf = 0;
    for (int it = 0; it < cnt; ++it) {
        // ---- prefetch next edge ----
        float wn = 0.0f;
        float mn[M0d];
        const bool hasn = (it + 1 < cnt);
        if (hasn) {
            int e2 = perm[beg + it + 1];
            if (t < 125) wn = wigner_inv[(size_t)e2 * 625 + wi * 25 + wco];
            const float* mb2 = m0s + (size_t)e2 * (M0d * C_DIM) + t;
            #pragma unroll
            for (int a = 0; a < M0d; ++a) mn[a] = mb2[a * C_DIM];
        } else {
            #pragma unroll
            for (int a = 0; a < M0d; ++a) mn[a] = 0.0f;
        }

        // ---- stage current W to LDS (double-buffered: one barrier/edge) ----
        if (t < 125) s_w[buf][wa][wi] = wc;
        __syncthreads();

        // ---- rank-5 update: acc[i] += sum_a W[i,a] * m[a] ----
        #pragma unroll
        for (int a = 0; a < M0d; ++a) {
            const float ma = mc[a];
            const float4* w4 = (const float4*)s_w[buf][a];
            #pragma unroll
            for (int i4 = 0; i4 < 7; ++i4) {
                float4 w = w4[i4];
                acc[i4 * 4 + 0] += w.x * ma;
                acc[i4 * 4 + 1] += w.y * ma;
                acc[i4 * 4 + 2] += w.z * ma;
                acc[i4 * 4 + 3] += w.w * ma;
            }
        }

        wc = wn;
        #pragma unroll
        for (int a = 0; a < M0d; ++a) mc[a] = mn[a];
        buf ^= 1;
    }

    const size_t base = (size_t)n * (NCOEF * C_DIM) + t;
    #pragma unroll
    for (int i = 0; i < NCOEF; ++i)
        out[base + i * C_DIM] = x[base + i * C_DIM] + acc[i];
}

// ---------------- Fallback (round-1 atomic version) ----------------
constexpr int FEB = 8;

__global__ __launch_bounds__(BT) void edge_degree_fallback(
    const float* __restrict__ x_edge, const float* __restrict__ edge_distance,
    const float* __restrict__ wigner_inv, const int* __restrict__ edge_index,
    const float* __restrict__ w1, const float* __restrict__ b1,
    const float* __restrict__ g1, const float* __restrict__ be1,
    const float* __restrict__ w2, const float* __restrict__ b2,
    const float* __restrict__ g2, const float* __restrict__ be2,
    const float* __restrict__ w3, const float* __restrict__ b3,
    const int* __restrict__ node_offset_p, float* __restrict__ out, int E)
{
    __shared__ float s_xe[FEB][C_DIM];
    __shared__ float s_h1[FEB][64];
    __shared__ float s_h2[FEB][64];
    __shared__ float s_wig[FEB][NCOEF * M0d];
    __shared__ float s_scale[FEB];
    __shared__ int   s_dst[FEB];

    const int t = threadIdx.x;
    const int g0 = blockIdx.x * FEB;
    const int ne = (E - g0) < FEB ? (E - g0) : FEB;

    {
        const float* src = x_edge + (size_t)g0 * C_DIM;
        for (int f = t; f < FEB * C_DIM; f += BT) {
            int e = f >> 7;
            ((float*)s_xe)[f] = (e < ne) ? src[f] : 0.0f;
        }
    }
    {
        const int wcol_[M0d] = {0, 2, 6, 12, 20};
        for (int f = t; f < FEB * NCOEF * M0d; f += BT) {
            int e = f / 125, r = f - e * 125, i = r / 5, a = r - i * 5;
            float v = 0.0f;
            if (e < ne)
                v = wigner_inv[((size_t)(g0 + e)) * (NCOEF * NCOEF) + i * NCOEF + wcol_[a]];
            s_wig[e][r] = v;
        }
    }
    if (t < FEB) {
        if (t < ne) {
            float d = edge_distance[g0 + t] * INV_CUTOFF;
            float d2 = d * d, d5 = d2 * d2 * d;
            float env = 1.0f + d5 * (-21.0f + d * (35.0f + d * (-15.0f)));
            s_scale[t] = ((d < 1.0f) ? env : 0.0f) * INV_RESCALE;
            s_dst[t] = edge_index[E + g0 + t] - node_offset_p[0];
        } else { s_scale[t] = 0.0f; s_dst[t] = 0; }
    }
    __syncthreads();

    const int wv = t >> 6, j = t & 63;
    {
        float acc0 = b1[j], acc1 = acc0;
        for (int k = 0; k < C_DIM; ++k) {
            float w = w1[k * 64 + j];
            acc0 += s_xe[wv][k] * w;
            acc1 += s_xe[wv + 4][k] * w;
        }
        const float g = g1[j], be = be1[j];
        s_h1[wv][j]     = ln_silu(acc0, g, be);
        s_h1[wv + 4][j] = ln_silu(acc1, g, be);
    }
    __syncthreads();
    {
        float acc0 = b2[j], acc1 = acc0;
        for (int k = 0; k < 64; ++k) {
            float w = w2[k * 64 + j];
            acc0 += s_h1[wv][k] * w;
            acc1 += s_h1[wv + 4][k] * w;
        }
        const float g = g2[j], be = be2[j];
        s_h2[wv][j]     = ln_silu(acc0, g, be);
        s_h2[wv + 4][j] = ln_silu(acc1, g, be);
    }
    __syncthreads();

    const int c = t & 127, half = t >> 7;
    float m0r[4][M0d];
    #pragma unroll
    for (int a = 0; a < M0d; ++a) {
        float bb = b3[a * C_DIM + c];
        float a0 = bb, a1 = bb, a2 = bb, a3 = bb;
        const float* w3c = w3 + a * C_DIM + c;
        for (int k = 0; k < 64; ++k) {
            float w = w3c[k * (M0d * C_DIM)];
            a0 += s_h2[half + 0][k] * w;
            a1 += s_h2[half + 2][k] * w;
            a2 += s_h2[half + 4][k] * w;
            a3 += s_h2[half + 6][k] * w;
        }
        m0r[0][a] = a0; m0r[1][a] = a1; m0r[2][a] = a2; m0r[3][a] = a3;
    }
    #pragma unroll
    for (int ei = 0; ei < 4; ++ei) {
        const int e = half + 2 * ei;
        if (e >= ne) continue;
        const float sc = s_scale[e];
        float* obase = out + (size_t)s_dst[e] * (NCOEF * C_DIM) + c;
        #pragma unroll
        for (int i = 0; i < NCOEF; ++i) {
            const float* wg = &s_wig[e][i * M0d];
            float v = wg[0] * m0r[ei][0] + wg[1] * m0r[ei][1] + wg[2] * m0r[ei][2]
                    + wg[3] * m0r[ei][3] + wg[4] * m0r[ei][4];
            atomicAdd(obase + i * C_DIM, v * sc);
        }
    }
}

extern "C" void kernel_launch(void* const* d_in, const int* in_sizes, int n_in,
                              void* d_out, int out_size, void* d_ws, size_t ws_size,
                              hipStream_t stream)
{
    const float* x             = (const float*)d_in[0];
    const float* x_edge        = (const float*)d_in[1];
    const float* edge_distance = (const float*)d_in[2];
    const float* wigner_inv    = (const float*)d_in[3];
    const int*   edge_index    = (const int*)d_in[4];
    const float* w1  = (const float*)d_in[5];
    const float* b1  = (const float*)d_in[6];
    const float* g1  = (const float*)d_in[7];
    const float* be1 = (const float*)d_in[8];
    const float* w2  = (const float*)d_in[9];
    const float* b2  = (const float*)d_in[10];
    const float* g2  = (const float*)d_in[11];
    const float* be2 = (const float*)d_in[12];
    const float* w3  = (const float*)d_in[13];
    const float* b3  = (const float*)d_in[14];
    const int*   node_offset = (const int*)d_in[15];

    float* out = (float*)d_out;
    const int E = in_sizes[1] / C_DIM;
    const int N = in_sizes[0] / (NCOEF * C_DIM);

    const size_t m0_bytes  = (size_t)E * (M0d * C_DIM) * 4;
    const size_t cnt_off   = m0_bytes;
    const size_t cur_off   = cnt_off + (size_t)N * 4;
    const size_t offs_off  = cur_off + (size_t)N * 4;
    const size_t perm_off  = offs_off + (size_t)(N + 1) * 4;
    const size_t need      = perm_off + (size_t)E * 4;

    if (ws_size >= need) {
        char* ws  = (char*)d_ws;
        float* m0s = (float*)ws;
        int* cnt  = (int*)(ws + cnt_off);
        int* cur  = (int*)(ws + cur_off);
        int* offs = (int*)(ws + offs_off);
        int* perm = (int*)(ws + perm_off);

        hipMemsetAsync(cnt, 0, (size_t)N * 8, stream);  // cnt + cur (adjacent)

        count_kernel<<<(E + 255) / 256, 256, 0, stream>>>(edge_index, node_offset, cnt, E, N);
        scan_kernel<<<1, 256, 0, stream>>>(cnt, offs, N);
        fill_kernel<<<(E + 255) / 256, 256, 0, stream>>>(edge_index, node_offset, offs, cur, perm, E, N);

        mlp_kernel<<<(E + EB - 1) / EB, BT, 0, stream>>>(
            x_edge, edge_distance,
            w1, b1, g1, be1, w2, b2, g2, be2, w3, b3, m0s, E);

        gather_kernel<<<N, 128, 0, stream>>>(x, m0s, wigner_inv, perm, offs, out, N);
    } else {
        hipMemcpyAsync(out, x, (size_t)out_size * sizeof(float),
                       hipMemcpyDeviceToDevice, stream);
        edge_degree_fallback<<<(E + FEB - 1) / FEB, BT, 0, stream>>>(
            x_edge, edge_distance, wigner_inv, edge_index,
            w1, b1, g1, be1, w2, b2, g2, be2, w3, b3,
            node_offset, out, E);
    }
}

// Round 4
// 147.541 us; speedup vs baseline: 3.0691x; 1.5247x over previous
//
#include <hip/hip_runtime.h>
#include <cstddef>

// EdgeDegreeEmbedding fused pipeline for MI355X (gfx950)
//
//   h1 = silu(LN(x_edge @ w1 + b1))          [E,64]
//   h2 = silu(LN(h1 @ w2 + b2))              [E,64]
//   m0 = (h2 @ w3 + b3) * env(d/12)/5        [E,5,128]
//   out[dst[e], i, c] += sum_a wigner_inv[e, i, a*(a+1)] * m0[e,a,c]
//   out initialized to x.
//
// Round-4: MLP moved to bf16 MFMA (16x16x32), operand-swapped so the
// edge index rides lane&15 (per-edge scale = 1 VGPR, float4 stores,
// 2-shuffle LayerNorm). Weights pre-transposed/converted to bf16 in ws.

constexpr int C_DIM   = 128;
constexpr int NCOEF   = 25;
constexpr int M0d     = 5;
constexpr float EPS_LN      = 1e-5f;
constexpr float INV_CUTOFF  = 1.0f / 12.0f;
constexpr float INV_RESCALE = 0.2f;

typedef __attribute__((ext_vector_type(8))) short short8;   // 8 bf16 (4 VGPR)
typedef __attribute__((ext_vector_type(4))) short short4v;  // 4 bf16 (2 VGPR)
typedef __attribute__((ext_vector_type(4))) float f32x4;

__device__ __forceinline__ short f2bf(float f) {
    unsigned u = __float_as_uint(f);
    unsigned r = u + 0x7FFFu + ((u >> 16) & 1u);   // round-to-nearest-even
    return (short)(r >> 16);
}

__device__ __forceinline__ float silu(float z) {
    return z / (1.0f + __expf(-z));
}

// ---------------- Kernel P: weights -> bf16, transposed [n][k] ----------------
__global__ __launch_bounds__(256) void prep_weights(
    const float* __restrict__ w1, const float* __restrict__ w2,
    const float* __restrict__ w3,
    short* __restrict__ w1T, short* __restrict__ w2T, short* __restrict__ w3T)
{
    int i = blockIdx.x * 256 + threadIdx.x;
    if (i < 64 * 128) {             // w1T[n*128+k] = w1[k*64+n]
        int n = i >> 7, k = i & 127;
        w1T[i] = f2bf(w1[k * 64 + n]);
    }
    if (i < 64 * 64) {              // w2T[n*64+k] = w2[k*64+n]
        int n = i >> 6, k = i & 63;
        w2T[i] = f2bf(w2[k * 64 + n]);
    }
    if (i < 640 * 64) {             // w3T[n*64+k] = w3[k*640+n]
        int n = i >> 6, k = i & 63;
        w3T[i] = f2bf(w3[k * 640 + n]);
    }
}

// ---------------- Kernel A: MFMA radial MLP -> scaled m0 ----------------
// 64 edges/block, 4 independent waves, 16 edges/wave.
// MFMA convention (16x16x32 bf16): A: m=l&15, k=8*(l>>4)+j (from wT[n][k]);
// B: n=l&15, k=8*(l>>4)+j; D: col(n)=l&15, row(m)=(l>>4)*4+r.
// Here A=weights (m=out-channel), B=activations (n=edge).
__global__ __launch_bounds__(256) void mlp_mfma_kernel(
    const float* __restrict__ x_edge,        // [E,128]
    const float* __restrict__ edge_distance, // [E]
    const short* __restrict__ w1T,           // [64][128] bf16
    const float* __restrict__ b1,
    const float* __restrict__ g1, const float* __restrict__ be1,
    const short* __restrict__ w2T,           // [64][64] bf16
    const float* __restrict__ b2,
    const float* __restrict__ g2, const float* __restrict__ be2,
    const short* __restrict__ w3T,           // [640][64] bf16
    const float* __restrict__ b3,
    float*       __restrict__ m0s,           // [E,5,128] == [E,640]
    int E)
{
    __shared__ short s_h[4][1024];   // per-wave 16x64 bf16, XOR-swizzled (8 KB)

    const int t  = threadIdx.x;
    const int w  = t >> 6;
    const int l  = t & 63;
    const int e16 = l & 15;          // edge within wave tile / A row within tile
    const int g   = l >> 4;          // k-group
    const int g0  = blockIdx.x * 64;
    const int row = g0 + w * 16 + e16;
    const int rowc = row < E ? row : (E - 1);
    const bool valid = row < E;
    const int swz = (e16 & 7) << 4;  // byte-XOR within 128B row

    char* lds = (char*)&s_h[w][0];

    // per-edge envelope scale (edge = e16, 4 lanes share)
    float sc;
    {
        float d  = edge_distance[rowc] * INV_CUTOFF;
        float d2 = d * d;
        float d5 = d2 * d2 * d;
        float env = 1.0f + d5 * (-21.0f + d * (35.0f + d * (-15.0f)));
        sc = ((d < 1.0f) ? env : 0.0f) * INV_RESCALE;
    }

    // ---- B1 fragments from x_edge (f32 -> bf16), K=128 -> 4 k-tiles ----
    short8 bx[4];
    {
        const float* xr = x_edge + (size_t)rowc * C_DIM + 8 * g;
        #pragma unroll
        for (int kt = 0; kt < 4; ++kt) {
            float4 f0 = *(const float4*)(xr + kt * 32);
            float4 f1 = *(const float4*)(xr + kt * 32 + 4);
            short8 v;
            v[0] = f2bf(f0.x); v[1] = f2bf(f0.y); v[2] = f2bf(f0.z); v[3] = f2bf(f0.w);
            v[4] = f2bf(f1.x); v[5] = f2bf(f1.y); v[6] = f2bf(f1.z); v[7] = f2bf(f1.w);
            bx[kt] = v;
        }
    }

    // ---- Layer 1: 64 out channels = 4 n-tiles ----
    f32x4 acc1[4];
    #pragma unroll
    for (int nt = 0; nt < 4; ++nt) {
        float4 bv = *(const float4*)(b1 + nt * 16 + 4 * g);
        f32x4 acc = {bv.x, bv.y, bv.z, bv.w};
        #pragma unroll
        for (int kt = 0; kt < 4; ++kt) {
            short8 aw = *(const short8*)(w1T + (nt * 16 + e16) * 128 + kt * 32 + 8 * g);
            acc = __builtin_amdgcn_mfma_f32_16x16x32_bf16(aw, bx[kt], acc, 0, 0, 0);
        }
        acc1[nt] = acc;
    }

    // ---- LN + SiLU (per edge: reduce in-lane 16 + lanes l^16, l^32) ----
    {
        float s = 0.0f;
        #pragma unroll
        for (int nt = 0; nt < 4; ++nt)
            s += acc1[nt][0] + acc1[nt][1] + acc1[nt][2] + acc1[nt][3];
        s += __shfl_xor(s, 16);
        s += __shfl_xor(s, 32);
        float mu = s * (1.0f / 64.0f);
        float q = 0.0f;
        #pragma unroll
        for (int nt = 0; nt < 4; ++nt) {
            #pragma unroll
            for (int r = 0; r < 4; ++r) {
                float d = acc1[nt][r] - mu;
                q += d * d;
            }
        }
        q += __shfl_xor(q, 16);
        q += __shfl_xor(q, 32);
        float rstd = rsqrtf(q * (1.0f / 64.0f) + EPS_LN);
        #pragma unroll
        for (int nt = 0; nt < 4; ++nt) {
            float4 gv = *(const float4*)(g1 + nt * 16 + 4 * g);
            float4 bv = *(const float4*)(be1 + nt * 16 + 4 * g);
            short4v hv;
            hv[0] = f2bf(silu((acc1[nt][0] - mu) * rstd * gv.x + bv.x));
            hv[1] = f2bf(silu((acc1[nt][1] - mu) * rstd * gv.y + bv.y));
            hv[2] = f2bf(silu((acc1[nt][2] - mu) * rstd * gv.z + bv.z));
            hv[3] = f2bf(silu((acc1[nt][3] - mu) * rstd * gv.w + bv.w));
            *(short4v*)(lds + e16 * 128 + ((nt * 32 + 8 * g) ^ swz)) = hv;
        }
    }
    asm volatile("s_waitcnt lgkmcnt(0)" ::: "memory");

    // ---- B2 fragments from LDS (h1), K=64 -> 2 k-tiles ----
    short8 bh[2];
    #pragma unroll
    for (int kt = 0; kt < 2; ++kt)
        bh[kt] = *(const short8*)(lds + e16 * 128 + ((kt * 64 + 16 * g) ^ swz));

    // ---- Layer 2 ----
    f32x4 acc2[4];
    #pragma unroll
    for (int nt = 0; nt < 4; ++nt) {
        float4 bv = *(const float4*)(b2 + nt * 16 + 4 * g);
        f32x4 acc = {bv.x, bv.y, bv.z, bv.w};
        #pragma unroll
        for (int kt = 0; kt < 2; ++kt) {
            short8 aw = *(const short8*)(w2T + (nt * 16 + e16) * 64 + kt * 32 + 8 * g);
            acc = __builtin_amdgcn_mfma_f32_16x16x32_bf16(aw, bh[kt], acc, 0, 0, 0);
        }
        acc2[nt] = acc;
    }

    {
        float s = 0.0f;
        #pragma unroll
        for (int nt = 0; nt < 4; ++nt)
            s += acc2[nt][0] + acc2[nt][1] + acc2[nt][2] + acc2[nt][3];
        s += __shfl_xor(s, 16);
        s += __shfl_xor(s, 32);
        float mu = s * (1.0f / 64.0f);
        float q = 0.0f;
        #pragma unroll
        for (int nt = 0; nt < 4; ++nt) {
            #pragma unroll
            for (int r = 0; r < 4; ++r) {
                float d = acc2[nt][r] - mu;
                q += d * d;
            }
        }
        q += __shfl_xor(q, 16);
        q += __shfl_xor(q, 32);
        float rstd = rsqrtf(q * (1.0f / 64.0f) + EPS_LN);
        #pragma unroll
        for (int nt = 0; nt < 4; ++nt) {
            float4 gv = *(const float4*)(g2 + nt * 16 + 4 * g);
            float4 bv = *(const float4*)(be2 + nt * 16 + 4 * g);
            short4v hv;
            hv[0] = f2bf(silu((acc2[nt][0] - mu) * rstd * gv.x + bv.x));
            hv[1] = f2bf(silu((acc2[nt][1] - mu) * rstd * gv.y + bv.y));
            hv[2] = f2bf(silu((acc2[nt][2] - mu) * rstd * gv.z + bv.z));
            hv[3] = f2bf(silu((acc2[nt][3] - mu) * rstd * gv.w + bv.w));
            *(short4v*)(lds + e16 * 128 + ((nt * 32 + 8 * g) ^ swz)) = hv;
        }
    }
    asm volatile("s_waitcnt lgkmcnt(0)" ::: "memory");

    // ---- B3 fragments from LDS (h2) ----
    short8 bh2[2];
    #pragma unroll
    for (int kt = 0; kt < 2; ++kt)
        bh2[kt] = *(const short8*)(lds + e16 * 128 + ((kt * 64 + 16 * g) ^ swz));

    // ---- Layer 3: 640 out channels = 40 n-tiles, scale + store ----
    float* orow = m0s + (size_t)row * 640 + 4 * g;
    #pragma unroll 8
    for (int nt = 0; nt < 40; ++nt) {
        float4 bv = *(const float4*)(b3 + nt * 16 + 4 * g);
        f32x4 acc = {bv.x, bv.y, bv.z, bv.w};
        short8 aw0 = *(const short8*)(w3T + (nt * 16 + e16) * 64 + 8 * g);
        short8 aw1 = *(const short8*)(w3T + (nt * 16 + e16) * 64 + 32 + 8 * g);
        acc = __builtin_amdgcn_mfma_f32_16x16x32_bf16(aw0, bh2[0], acc, 0, 0, 0);
        acc = __builtin_amdgcn_mfma_f32_16x16x32_bf16(aw1, bh2[1], acc, 0, 0, 0);
        if (valid) {
            float4 o;
            o.x = acc[0] * sc; o.y = acc[1] * sc; o.z = acc[2] * sc; o.w = acc[3] * sc;
            *(float4*)(orow + nt * 16) = o;
        }
    }
}

// ---------------- Binning ----------------
__global__ __launch_bounds__(256) void count_kernel(
    const int* __restrict__ edge_index, const int* __restrict__ noff,
    int* __restrict__ cnt, int E, int N)
{
    int e = blockIdx.x * 256 + threadIdx.x;
    if (e < E) {
        int d = edge_index[E + e] - noff[0];
        if (d >= 0 && d < N) atomicAdd(&cnt[d], 1);
    }
}

__global__ __launch_bounds__(256) void scan_kernel(
    const int* __restrict__ cnt, int* __restrict__ offs, int N)
{
    __shared__ int buf[256];
    __shared__ int s_run;
    const int t = threadIdx.x;
    if (t == 0) { offs[0] = 0; s_run = 0; }
    __syncthreads();
    for (int base = 0; base < N; base += 256) {
        int v = (base + t < N) ? cnt[base + t] : 0;
        buf[t] = v;
        __syncthreads();
        for (int off = 1; off < 256; off <<= 1) {
            int u = (t >= off) ? buf[t - off] : 0;
            __syncthreads();
            buf[t] += u;
            __syncthreads();
        }
        if (base + t < N) offs[base + t + 1] = s_run + buf[t];
        __syncthreads();
        if (t == 255) s_run += buf[255];
        __syncthreads();
    }
}

__global__ __launch_bounds__(256) void fill_kernel(
    const int* __restrict__ edge_index, const int* __restrict__ noff,
    const int* __restrict__ offs, int* __restrict__ cur,
    int* __restrict__ perm, int E, int N)
{
    int e = blockIdx.x * 256 + threadIdx.x;
    if (e < E) {
        int d = edge_index[E + e] - noff[0];
        if (d >= 0 && d < N) {
            int p = atomicAdd(&cur[d], 1);
            perm[offs[d] + p] = e;
        }
    }
}

// ---------------- Kernel B: per-node gather, software-pipelined ----------------
__global__ __launch_bounds__(128) void gather_kernel(
    const float* __restrict__ x,          // [N,25,128]
    const float* __restrict__ m0s,        // [E,5,128] (already scaled)
    const float* __restrict__ wigner_inv, // [E,25,25]
    const int*   __restrict__ perm, const int* __restrict__ offs,
    float*       __restrict__ out, int N)
{
    __shared__ float s_w[2][M0d][28];

    const int n = blockIdx.x;
    const int t = threadIdx.x;          // channel c; also W-load lane
    const int wa = t % 5;
    const int wi = t / 5;
    const int wco = wa * (wa + 1);

    if (t < 2 * M0d * 3) {
        int b = t / 15, r = t % 15;
        s_w[b][r / 3][25 + r % 3] = 0.0f;
    }

    float acc[28];
    #pragma unroll
    for (int i = 0; i < 28; ++i) acc[i] = 0.0f;

    const int beg = offs[n], end = offs[n + 1];
    const int cnt = end - beg;

    float wc = 0.0f;
    float mc[M0d];
    #pragma unroll
    for (int a = 0; a < M0d; ++a) mc[a] = 0.0f;

    if (cnt > 0) {
        int e = perm[beg];
        if (t < 125) wc = wigner_inv[(size_t)e * 625 + wi * 25 + wco];
        const float* mb = m0s + (size_t)e * (M0d * C_DIM) + t;
        #pragma unroll
        for (int a = 0; a < M0d; ++a) mc[a] = mb[a * C_DIM];
    }

    int buf = 0;
    for (int it = 0; it < cnt; ++it) {
        float wn = 0.0f;
        float mn[M0d];
        const bool hasn = (it + 1 < cnt);
        if (hasn) {
            int e2 = perm[beg + it + 1];
            if (t < 125) wn = wigner_inv[(size_t)e2 * 625 + wi * 25 + wco];
            const float* mb2 = m0s + (size_t)e2 * (M0d * C_DIM) + t;
            #pragma unroll
            for (int a = 0; a < M0d; ++a) mn[a] = mb2[a * C_DIM];
        } else {
            #pragma unroll
            for (int a = 0; a < M0d; ++a) mn[a] = 0.0f;
        }

        if (t < 125) s_w[buf][wa][wi] = wc;
        __syncthreads();

        #pragma unroll
        for (int a = 0; a < M0d; ++a) {
            const float ma = mc[a];
            const float4* w4 = (const float4*)s_w[buf][a];
            #pragma unroll
            for (int i4 = 0; i4 < 7; ++i4) {
                float4 w = w4[i4];
                acc[i4 * 4 + 0] += w.x * ma;
                acc[i4 * 4 + 1] += w.y * ma;
                acc[i4 * 4 + 2] += w.z * ma;
                acc[i4 * 4 + 3] += w.w * ma;
            }
        }

        wc = wn;
        #pragma unroll
        for (int a = 0; a < M0d; ++a) mc[a] = mn[a];
        buf ^= 1;
    }

    const size_t base = (size_t)n * (NCOEF * C_DIM) + t;
    #pragma unroll
    for (int i = 0; i < NCOEF; ++i)
        out[base + i * C_DIM] = x[base + i * C_DIM] + acc[i];
}

// ---------------- Fallback (round-1 atomic version) ----------------
constexpr int FEB = 8;
constexpr int BT  = 256;

__device__ __forceinline__ float ln_silu(float v, float g, float be) {
    float s = v;
    #pragma unroll
    for (int o = 32; o; o >>= 1) s += __shfl_xor(s, o, 64);
    float mu = s * (1.0f / 64.0f);
    float dv = v - mu;
    float q  = dv * dv;
    #pragma unroll
    for (int o = 32; o; o >>= 1) q += __shfl_xor(q, o, 64);
    float rstd = rsqrtf(q * (1.0f / 64.0f) + EPS_LN);
    float z = dv * rstd * g + be;
    return z / (1.0f + __expf(-z));
}

__global__ __launch_bounds__(BT) void edge_degree_fallback(
    const float* __restrict__ x_edge, const float* __restrict__ edge_distance,
    const float* __restrict__ wigner_inv, const int* __restrict__ edge_index,
    const float* __restrict__ w1, const float* __restrict__ b1,
    const float* __restrict__ g1, const float* __restrict__ be1,
    const float* __restrict__ w2, const float* __restrict__ b2,
    const float* __restrict__ g2, const float* __restrict__ be2,
    const float* __restrict__ w3, const float* __restrict__ b3,
    const int* __restrict__ node_offset_p, float* __restrict__ out, int E)
{
    __shared__ float s_xe[FEB][C_DIM];
    __shared__ float s_h1[FEB][64];
    __shared__ float s_h2[FEB][64];
    __shared__ float s_wig[FEB][NCOEF * M0d];
    __shared__ float s_scale[FEB];
    __shared__ int   s_dst[FEB];

    const int t = threadIdx.x;
    const int g0 = blockIdx.x * FEB;
    const int ne = (E - g0) < FEB ? (E - g0) : FEB;

    {
        const float* src = x_edge + (size_t)g0 * C_DIM;
        for (int f = t; f < FEB * C_DIM; f += BT) {
            int e = f >> 7;
            ((float*)s_xe)[f] = (e < ne) ? src[f] : 0.0f;
        }
    }
    {
        const int wcol_[M0d] = {0, 2, 6, 12, 20};
        for (int f = t; f < FEB * NCOEF * M0d; f += BT) {
            int e = f / 125, r = f - e * 125, i = r / 5, a = r - i * 5;
            float v = 0.0f;
            if (e < ne)
                v = wigner_inv[((size_t)(g0 + e)) * (NCOEF * NCOEF) + i * NCOEF + wcol_[a]];
            s_wig[e][r] = v;
        }
    }
    if (t < FEB) {
        if (t < ne) {
            float d = edge_distance[g0 + t] * INV_CUTOFF;
            float d2 = d * d, d5 = d2 * d2 * d;
            float env = 1.0f + d5 * (-21.0f + d * (35.0f + d * (-15.0f)));
            s_scale[t] = ((d < 1.0f) ? env : 0.0f) * INV_RESCALE;
            s_dst[t] = edge_index[E + g0 + t] - node_offset_p[0];
        } else { s_scale[t] = 0.0f; s_dst[t] = 0; }
    }
    __syncthreads();

    const int wv = t >> 6, j = t & 63;
    {
        float acc0 = b1[j], acc1 = acc0;
        for (int k = 0; k < C_DIM; ++k) {
            float w = w1[k * 64 + j];
            acc0 += s_xe[wv][k] * w;
            acc1 += s_xe[wv + 4][k] * w;
        }
        const float g = g1[j], be = be1[j];
        s_h1[wv][j]     = ln_silu(acc0, g, be);
        s_h1[wv + 4][j] = ln_silu(acc1, g, be);
    }
    __syncthreads();
    {
        float acc0 = b2[j], acc1 = acc0;
        for (int k = 0; k < 64; ++k) {
            float w = w2[k * 64 + j];
            acc0 += s_h1[wv][k] * w;
            acc1 += s_h1[wv + 4][k] * w;
        }
        const float g = g2[j], be = be2[j];
        s_h2[wv][j]     = ln_silu(acc0, g, be);
        s_h2[wv + 4][j] = ln_silu(acc1, g, be);
    }
    __syncthreads();

    const int c = t & 127, half = t >> 7;
    float m0r[4][M0d];
    #pragma unroll
    for (int a = 0; a < M0d; ++a) {
        float bb = b3[a * C_DIM + c];
        float a0 = bb, a1 = bb, a2 = bb, a3 = bb;
        const float* w3c = w3 + a * C_DIM + c;
        for (int k = 0; k < 64; ++k) {
            float w = w3c[k * (M0d * C_DIM)];
            a0 += s_h2[half + 0][k] * w;
            a1 += s_h2[half + 2][k] * w;
            a2 += s_h2[half + 4][k] * w;
            a3 += s_h2[half + 6][k] * w;
        }
        m0r[0][a] = a0; m0r[1][a] = a1; m0r[2][a] = a2; m0r[3][a] = a3;
    }
    #pragma unroll
    for (int ei = 0; ei < 4; ++ei) {
        const int e = half + 2 * ei;
        if (e >= ne) continue;
        const float sc = s_scale[e];
        float* obase = out + (size_t)s_dst[e] * (NCOEF * C_DIM) + c;
        #pragma unroll
        for (int i = 0; i < NCOEF; ++i) {
            const float* wg = &s_wig[e][i * M0d];
            float v = wg[0] * m0r[ei][0] + wg[1] * m0r[ei][1] + wg[2] * m0r[ei][2]
                    + wg[3] * m0r[ei][3] + wg[4] * m0r[ei][4];
            atomicAdd(obase + i * C_DIM, v * sc);
        }
    }
}

extern "C" void kernel_launch(void* const* d_in, const int* in_sizes, int n_in,
                              void* d_out, int out_size, void* d_ws, size_t ws_size,
                              hipStream_t stream)
{
    const float* x             = (const float*)d_in[0];
    const float* x_edge        = (const float*)d_in[1];
    const float* edge_distance = (const float*)d_in[2];
    const float* wigner_inv    = (const float*)d_in[3];
    const int*   edge_index    = (const int*)d_in[4];
    const float* w1  = (const float*)d_in[5];
    const float* b1  = (const float*)d_in[6];
    const float* g1  = (const float*)d_in[7];
    const float* be1 = (const float*)d_in[8];
    const float* w2  = (const float*)d_in[9];
    const float* b2  = (const float*)d_in[10];
    const float* g2  = (const float*)d_in[11];
    const float* be2 = (const float*)d_in[12];
    const float* w3  = (const float*)d_in[13];
    const float* b3  = (const float*)d_in[14];
    const int*   node_offset = (const int*)d_in[15];

    float* out = (float*)d_out;
    const int E = in_sizes[1] / C_DIM;
    const int N = in_sizes[0] / (NCOEF * C_DIM);

    size_t off = 0;
    const size_t m0_off   = off; off += (size_t)E * 640 * 4;
    const size_t cnt_off  = off; off += (size_t)N * 4;
    const size_t cur_off  = off; off += (size_t)N * 4;
    const size_t offs_off = off; off += (size_t)(N + 1) * 4;
    const size_t perm_off = off; off += (size_t)E * 4;
    off = (off + 255) & ~(size_t)255;
    const size_t w1T_off  = off; off += 64 * 128 * 2;
    const size_t w2T_off  = off; off += 64 * 64 * 2;
    const size_t w3T_off  = off; off += 640 * 64 * 2;
    const size_t need     = off;

    if (ws_size >= need) {
        char* ws   = (char*)d_ws;
        float* m0s = (float*)(ws + m0_off);
        int* cnt   = (int*)(ws + cnt_off);
        int* cur   = (int*)(ws + cur_off);
        int* offs  = (int*)(ws + offs_off);
        int* perm  = (int*)(ws + perm_off);
        short* w1T = (short*)(ws + w1T_off);
        short* w2T = (short*)(ws + w2T_off);
        short* w3T = (short*)(ws + w3T_off);

        hipMemsetAsync(cnt, 0, (size_t)N * 8, stream);  // cnt + cur (adjacent)

        prep_weights<<<(640 * 64 + 255) / 256, 256, 0, stream>>>(w1, w2, w3, w1T, w2T, w3T);
        count_kernel<<<(E + 255) / 256, 256, 0, stream>>>(edge_index, node_offset, cnt, E, N);
        scan_kernel<<<1, 256, 0, stream>>>(cnt, offs, N);
        fill_kernel<<<(E + 255) / 256, 256, 0, stream>>>(edge_index, node_offset, offs, cur, perm, E, N);

        mlp_mfma_kernel<<<(E + 63) / 64, 256, 0, stream>>>(
            x_edge, edge_distance,
            w1T, b1, g1, be1, w2T, b2, g2, be2, w3T, b3, m0s, E);

        gather_kernel<<<N, 128, 0, stream>>>(x, m0s, wigner_inv, perm, offs, out, N);
    } else {
        hipMemcpyAsync(out, x, (size_t)out_size * sizeof(float),
                       hipMemcpyDeviceToDevice, stream);
        edge_degree_fallback<<<(E + FEB - 1) / FEB, BT, 0, stream>>>(
            x_edge, edge_distance, wigner_inv, edge_index,
            w1, b1, g1, be1, w2, b2, g2, be2, w3, b3,
            node_offset, out, E);
    }
}